// Round 1
// baseline (80.640 us; speedup 1.0000x reference)
//
#include <hip/hip_runtime.h>

#define N_PTS 4096
#define B_SZ 4
#define C_IN 64
#define C_OUT 128
#define NS 9
#define KTOT (C_IN * NS)   // 576
#define RAD2 0.04f
#define NT 64              // points per conv block
#define KT 64              // k-chunk

// ---------------- kernel 0: W [128][64][9] -> Wt [576][128] ----------------
__global__ void wt_kernel(const float* __restrict__ W, float* __restrict__ Wt) {
    int id = blockIdx.x * 256 + threadIdx.x;
    if (id >= KTOT * C_OUT) return;
    int o = id & (C_OUT - 1);
    int k = id >> 7;
    Wt[id] = W[o * KTOT + k];   // Wt[k*128+o] = W[o][k]
}

// ---------------- kernel 1: ball query, one wave per point ----------------
// Matches reference: d2 = (sq_n + sq_m) - 2*dot, all fp32 round-to-nearest,
// exclude d2 > r^2, take 9 smallest indices, pad with first hit.
__global__ void __launch_bounds__(256) ballq_kernel(const float* __restrict__ pcs,
                                                    int* __restrict__ idx) {
    int wid = (blockIdx.x * 256 + threadIdx.x) >> 6;   // global wave id = point id
    int lane = threadIdx.x & 63;
    int b = wid >> 12;            // / 4096
    int n = wid & (N_PTS - 1);
    const float* pb = pcs + (size_t)b * 3 * N_PTS;
    float cx = pb[n], cy = pb[N_PTS + n], cz = pb[2 * N_PTS + n];
    float csq = __fadd_rn(__fadd_rn(__fmul_rn(cx, cx), __fmul_rn(cy, cy)),
                          __fmul_rn(cz, cz));
    int* out = idx + (size_t)wid * NS;
    int cnt = 0, first = -1;
    for (int c0 = 0; c0 < N_PTS; c0 += 64) {
        int m = c0 + lane;
        float xm = pb[m], ym = pb[N_PTS + m], zm = pb[2 * N_PTS + m];
        float sqm = __fadd_rn(__fadd_rn(__fmul_rn(xm, xm), __fmul_rn(ym, ym)),
                              __fmul_rn(zm, zm));
        float dot = __fadd_rn(__fadd_rn(__fmul_rn(cx, xm), __fmul_rn(cy, ym)),
                              __fmul_rn(cz, zm));
        float d2 = __fsub_rn(__fadd_rn(csq, sqm), __fmul_rn(2.0f, dot));
        bool hit = !(d2 > RAD2);
        unsigned long long mask = __ballot(hit);
        if (mask) {
            if (first < 0) first = c0 + __ffsll(mask) - 1;   // uniform
            int pre = __popcll(mask & ((1ull << lane) - 1ull));
            if (hit) {
                int slot = cnt + pre;
                if (slot < NS) out[slot] = m;
            }
            cnt += __popcll(mask);                            // uniform
            if (cnt >= NS) break;                             // uniform break
        }
    }
    if (lane >= cnt && lane < NS) out[lane] = first;          // pad
}

// ---------------- kernel 2: gather + vector GEMM ----------------
// y[b][o][gn0+n] = sum_k Wt[k][o] * x[b][k/9][ idx[b][gn0+n][k%9] ] + bias[o]
__global__ void __launch_bounds__(512) conv_kernel(const float* __restrict__ x,
                                                   const float* __restrict__ Wt,
                                                   const int* __restrict__ idx,
                                                   const float* __restrict__ bias,
                                                   float* __restrict__ y) {
    __shared__ float Wlds[KT][C_OUT];   // 32 KB
    __shared__ float Xlds[KT][NT];      // 16 KB
    __shared__ int   ilds[NT * NS];     // 2.3 KB

    int t = threadIdx.x;
    int b = blockIdx.y;
    int gn0 = blockIdx.x * NT;

    for (int i = t; i < NT * NS; i += 512)
        ilds[i] = idx[((size_t)b * N_PTS + gn0) * NS + i];

    const float* xb = x + (size_t)b * C_IN * N_PTS;

    int ng = t & 31, og = t >> 5;   // og in [0,16)
    int n0 = ng * 2, o0 = og * 8;

    float acc[8][2];
    #pragma unroll
    for (int j = 0; j < 8; ++j) { acc[j][0] = 0.f; acc[j][1] = 0.f; }

    __syncthreads();

    for (int kc = 0; kc < KTOT; kc += KT) {
        // stage W chunk: 64x128 floats = 2048 float4, 4 per thread, coalesced
        #pragma unroll
        for (int i = 0; i < 4; ++i) {
            int flat = i * 512 + t;           // 0..2047
            int kk = flat >> 5;
            int p4 = (flat & 31) * 4;
            *(float4*)&Wlds[kk][p4] =
                *(const float4*)&Wt[(size_t)(kc + kk) * C_OUT + p4];
        }
        // stage X chunk: 64x64 gathered floats, 8 per thread
        #pragma unroll
        for (int i = 0; i < 8; ++i) {
            int flat = i * 512 + t;           // 0..4095
            int kk = flat >> 6;
            int nl = flat & 63;
            int k = kc + kk;
            int c = k / 9, s = k - c * 9;
            int g = ilds[nl * NS + s];
            Xlds[kk][nl] = xb[(size_t)c * N_PTS + g];
        }
        __syncthreads();
        #pragma unroll 4
        for (int kk = 0; kk < KT; ++kk) {
            float xv0 = Xlds[kk][n0];
            float xv1 = Xlds[kk][n0 + 1];
            float4 wa = *(const float4*)&Wlds[kk][o0];
            float4 wb = *(const float4*)&Wlds[kk][o0 + 4];
            float wv[8] = {wa.x, wa.y, wa.z, wa.w, wb.x, wb.y, wb.z, wb.w};
            #pragma unroll
            for (int j = 0; j < 8; ++j) {
                acc[j][0] = fmaf(wv[j], xv0, acc[j][0]);
                acc[j][1] = fmaf(wv[j], xv1, acc[j][1]);
            }
        }
        __syncthreads();
    }

    #pragma unroll
    for (int j = 0; j < 8; ++j) {
        int o = o0 + j;
        float bo = bias[o];
        float2 v = make_float2(acc[j][0] + bo, acc[j][1] + bo);
        *(float2*)&y[((size_t)b * C_OUT + o) * N_PTS + gn0 + n0] = v;
    }
}

extern "C" void kernel_launch(void* const* d_in, const int* in_sizes, int n_in,
                              void* d_out, int out_size, void* d_ws, size_t ws_size,
                              hipStream_t stream) {
    const float* x    = (const float*)d_in[0];   // [4,64,4096]
    const float* pcs  = (const float*)d_in[1];   // [4,3,4096]
    const float* W    = (const float*)d_in[2];   // [128,64,9]
    const float* bias = (const float*)d_in[3];   // [128]
    float* y = (float*)d_out;                    // [4,128,4096]

    int*   idx = (int*)d_ws;                               // 4*4096*9 ints = 2.25 MB
    float* Wt  = (float*)((char*)d_ws +
                          (size_t)B_SZ * N_PTS * NS * sizeof(int));  // 288 KB, 16B-aligned

    wt_kernel<<<(KTOT * C_OUT + 255) / 256, 256, 0, stream>>>(W, Wt);
    ballq_kernel<<<B_SZ * N_PTS / 4, 256, 0, stream>>>(pcs, idx);
    conv_kernel<<<dim3(N_PTS / NT, B_SZ), 512, 0, stream>>>(x, Wt, idx, bias, y);
}

// Round 2
// 35.263 us; speedup vs baseline: 2.2868x; 2.2868x over previous
//
#include <hip/hip_runtime.h>

#define N_PTS 4096
#define B_SZ 4
#define C_IN 64
#define C_OUT 128
#define NS 9
#define KTOT (C_IN * NS)   // 576
#define RAD2 0.04f

typedef __attribute__((ext_vector_type(8))) short bf16x8;
typedef __attribute__((ext_vector_type(4))) float f32x4;

__device__ inline ushort f2bf(float f) {
    union { float f; unsigned u; } v; v.f = f;
    unsigned r = (v.u + 0x7FFF + ((v.u >> 16) & 1)) >> 16;   // RTNE
    return (ushort)r;
}

// ---------------- kernel 0a: W [128][64][9] fp32 -> Wt [o][k] bf16, k = s*64+c ----
__global__ void wt_kernel(const float* __restrict__ W, ushort* __restrict__ Wt) {
    int id = blockIdx.x * 256 + threadIdx.x;
    if (id >= C_OUT * KTOT) return;
    int o = id / KTOT;
    int r = id - o * KTOT;        // s*64 + c
    int s = r >> 6, c = r & 63;
    Wt[id] = f2bf(W[o * KTOT + c * NS + s]);
}

// ---------------- kernel 0b: x [b][c][n] fp32 -> xT [b][n][c] bf16 ----------------
__global__ void __launch_bounds__(256) xt_kernel(const float* __restrict__ x,
                                                 ushort* __restrict__ xT) {
    __shared__ ushort tile[64][66];   // +2 pad: stride 66 hw -> conflict-free col read
    int b = blockIdx.y;
    int n0 = blockIdx.x * 64;
    int t = threadIdx.x;
    const float* xb = x + (size_t)b * C_IN * N_PTS;
    #pragma unroll
    for (int i = 0; i < 16; ++i) {
        int flat = i * 256 + t;
        int c = flat >> 6, n = flat & 63;
        tile[c][n] = f2bf(xb[(size_t)c * N_PTS + n0 + n]);   // coalesced read
    }
    __syncthreads();
    ushort* xTb = xT + ((size_t)b * N_PTS + n0) * C_IN;
    #pragma unroll
    for (int i = 0; i < 16; ++i) {
        int flat = i * 256 + t;
        int n = flat >> 6, c = flat & 63;
        xTb[(size_t)n * C_IN + c] = tile[c][n];              // coalesced write
    }
}

// ---------------- kernel 1: ball query (unchanged, verified) ----------------
__global__ void __launch_bounds__(256) ballq_kernel(const float* __restrict__ pcs,
                                                    int* __restrict__ idx) {
    int wid = (blockIdx.x * 256 + threadIdx.x) >> 6;
    int lane = threadIdx.x & 63;
    int b = wid >> 12;
    int n = wid & (N_PTS - 1);
    const float* pb = pcs + (size_t)b * 3 * N_PTS;
    float cx = pb[n], cy = pb[N_PTS + n], cz = pb[2 * N_PTS + n];
    float csq = __fadd_rn(__fadd_rn(__fmul_rn(cx, cx), __fmul_rn(cy, cy)),
                          __fmul_rn(cz, cz));
    int* out = idx + (size_t)wid * NS;
    int cnt = 0, first = -1;
    for (int c0 = 0; c0 < N_PTS; c0 += 64) {
        int m = c0 + lane;
        float xm = pb[m], ym = pb[N_PTS + m], zm = pb[2 * N_PTS + m];
        float sqm = __fadd_rn(__fadd_rn(__fmul_rn(xm, xm), __fmul_rn(ym, ym)),
                              __fmul_rn(zm, zm));
        float dot = __fadd_rn(__fadd_rn(__fmul_rn(cx, xm), __fmul_rn(cy, ym)),
                              __fmul_rn(cz, zm));
        float d2 = __fsub_rn(__fadd_rn(csq, sqm), __fmul_rn(2.0f, dot));
        bool hit = !(d2 > RAD2);
        unsigned long long mask = __ballot(hit);
        if (mask) {
            if (first < 0) first = c0 + __ffsll(mask) - 1;
            int pre = __popcll(mask & ((1ull << lane) - 1ull));
            if (hit) {
                int slot = cnt + pre;
                if (slot < NS) out[slot] = m;
            }
            cnt += __popcll(mask);
            if (cnt >= NS) break;
        }
    }
    if (lane >= cnt && lane < NS) out[lane] = first;
}

// ---------------- kernel 2: gathered MFMA GEMM ----------------
// y[b][o][gn0+n] = sum_{k=s*64+c} Wt[o][k] * xT[b][ idx[b][gn0+n][s] ][c] + bias[o]
__global__ void __launch_bounds__(256) conv_kernel(
    const ushort* __restrict__ xT, const ushort* __restrict__ Wt,
    const int* __restrict__ idx, const float* __restrict__ bias,
    float* __restrict__ y)
{
    __shared__ __align__(16) ushort Wlds[128 * 64];  // [o][k] swizzled, 16 KB
    __shared__ __align__(16) ushort Xlds[32 * 64];   // [n][k] swizzled, 4 KB
    __shared__ int ilds[32 * NS];

    const int t = threadIdx.x;
    const int lane = t & 63;
    const int wid = t >> 6;
    const int b = blockIdx.y;
    const int gn0 = blockIdx.x * 32;

    for (int i = t; i < 32 * NS; i += 256)
        ilds[i] = idx[((size_t)b * N_PTS + gn0) * NS + i];

    const ushort* xTb = xT + (size_t)b * N_PTS * C_IN;

    const int m0 = wid * 32;          // wave owns output rows m0..m0+31
    const int l4 = lane >> 4;         // 0..3 (k-group)
    const int arow = m0 + (lane & 15);
    const int brow = lane & 15;

    f32x4 acc[2][2];
    #pragma unroll
    for (int i = 0; i < 2; ++i)
        #pragma unroll
        for (int j = 0; j < 2; ++j)
            acc[i][j] = (f32x4){0.f, 0.f, 0.f, 0.f};

    __syncthreads();

    for (int s = 0; s < NS; ++s) {
        // ---- stage (reg-staged, swizzled LDS dest) ----
        int rowX = t >> 3, c16X = t & 7;
        int g = ilds[rowX * NS + s];
        uint4 xv = *(const uint4*)(xTb + ((size_t)g << 6) + (c16X << 3));
        uint4 wv[4];
        #pragma unroll
        for (int r = 0; r < 4; ++r) {
            int u = r * 256 + t;
            int row = u >> 3, c16 = u & 7;
            wv[r] = *(const uint4*)(Wt + row * KTOT + s * 64 + (c16 << 3));
        }
        *(uint4*)&Xlds[(rowX << 6) + ((c16X ^ (rowX & 7)) << 3)] = xv;
        #pragma unroll
        for (int r = 0; r < 4; ++r) {
            int u = r * 256 + t;
            int row = u >> 3, c16 = u & 7;
            *(uint4*)&Wlds[(row << 6) + ((c16 ^ (row & 7)) << 3)] = wv[r];
        }
        __syncthreads();

        // ---- compute: 2 k-halves, 4 mfma each ----
        #pragma unroll
        for (int h = 0; h < 2; ++h) {
            int c16 = h * 4 + l4;
            bf16x8 a0 = *(const bf16x8*)&Wlds[(arow << 6)        + ((c16 ^ (arow & 7)) << 3)];
            bf16x8 a1 = *(const bf16x8*)&Wlds[((arow + 16) << 6) + ((c16 ^ (arow & 7)) << 3)];
            bf16x8 b0 = *(const bf16x8*)&Xlds[(brow << 6)        + ((c16 ^ (brow & 7)) << 3)];
            bf16x8 b1 = *(const bf16x8*)&Xlds[((brow + 16) << 6) + ((c16 ^ (brow & 7)) << 3)];
            acc[0][0] = __builtin_amdgcn_mfma_f32_16x16x32_bf16(a0, b0, acc[0][0], 0, 0, 0);
            acc[0][1] = __builtin_amdgcn_mfma_f32_16x16x32_bf16(a0, b1, acc[0][1], 0, 0, 0);
            acc[1][0] = __builtin_amdgcn_mfma_f32_16x16x32_bf16(a1, b0, acc[1][0], 0, 0, 0);
            acc[1][1] = __builtin_amdgcn_mfma_f32_16x16x32_bf16(a1, b1, acc[1][1], 0, 0, 0);
        }
        __syncthreads();
    }

    // ---- epilogue: C/D layout col=lane&15, row=(lane>>4)*4+reg ----
    float* yb = y + (size_t)b * C_OUT * N_PTS + gn0;
    #pragma unroll
    for (int fm = 0; fm < 2; ++fm) {
        #pragma unroll
        for (int j = 0; j < 4; ++j) {
            int o = m0 + fm * 16 + l4 * 4 + j;
            float bo = bias[o];
            #pragma unroll
            for (int fn = 0; fn < 2; ++fn) {
                int n = fn * 16 + (lane & 15);
                yb[(size_t)o * N_PTS + n] = acc[fm][fn][j] + bo;
            }
        }
    }
}

extern "C" void kernel_launch(void* const* d_in, const int* in_sizes, int n_in,
                              void* d_out, int out_size, void* d_ws, size_t ws_size,
                              hipStream_t stream) {
    const float* x    = (const float*)d_in[0];   // [4,64,4096]
    const float* pcs  = (const float*)d_in[1];   // [4,3,4096]
    const float* W    = (const float*)d_in[2];   // [128,64,9]
    const float* bias = (const float*)d_in[3];   // [128]
    float* y = (float*)d_out;                    // [4,128,4096]

    int*    idx = (int*)d_ws;                                        // 589,824 B
    ushort* xT  = (ushort*)((char*)d_ws + 589824);                   // 2,097,152 B
    ushort* Wt  = (ushort*)((char*)d_ws + 589824 + 2097152);         // 147,456 B

    wt_kernel<<<(C_OUT * KTOT + 255) / 256, 256, 0, stream>>>(W, Wt);
    xt_kernel<<<dim3(N_PTS / 64, B_SZ), 256, 0, stream>>>(x, xT);
    ballq_kernel<<<B_SZ * N_PTS / 4, 256, 0, stream>>>(pcs, idx);
    conv_kernel<<<dim3(N_PTS / 32, B_SZ), 256, 0, stream>>>(xT, Wt, idx, bias, y);
}